// Round 1
// baseline (1515.057 us; speedup 1.0000x reference)
//
#include <hip/hip_runtime.h>
#include <math.h>

// Problem constants (match reference)
#define N_NODES 10000
#define N_EDGES 160000
#define D 256          // D_IN == HC1 == ED
#define H1 8
#define CH 32
#define TDIM 128       // time encoder dim
#define MSGD 128       // msg dim

static inline int ceildiv(int a, int b) { return (a + b - 1) / b; }

// ---------------- small prep kernels ----------------

__global__ void rel_kernel(const float* __restrict__ lu, const int* __restrict__ srcp,
                           const float* __restrict__ tt, float* __restrict__ rel, int E) {
  for (int i = blockIdx.x * blockDim.x + threadIdx.x; i < E; i += gridDim.x * blockDim.x)
    rel[i] = lu[srcp[i]] - tt[i];
}

__global__ void count_kernel(const int* __restrict__ dstp, int* __restrict__ deg, int E) {
  for (int i = blockIdx.x * blockDim.x + threadIdx.x; i < E; i += gridDim.x * blockDim.x)
    atomicAdd(&deg[dstp[i]], 1);
}

// single-block exclusive scan over deg[0..n) -> rowptr[0..n]
__global__ void scan_kernel(const int* __restrict__ deg, int* __restrict__ rowptr, int n) {
  __shared__ int sm[1024];
  __shared__ int carry_s;
  const int tid = threadIdx.x;
  if (tid == 0) carry_s = 0;
  __syncthreads();
  for (int base = 0; base < n; base += 1024) {
    int v = (base + tid < n) ? deg[base + tid] : 0;
    sm[tid] = v;
    __syncthreads();
    for (int off = 1; off < 1024; off <<= 1) {
      int y = 0;
      if (tid >= off) y = sm[tid - off];
      __syncthreads();
      sm[tid] += y;
      __syncthreads();
    }
    int incl = sm[tid];
    int carry = carry_s;
    if (base + tid < n) rowptr[base + tid] = carry + incl - v;
    __syncthreads();
    if (tid == 1023) carry_s = carry + incl;
    __syncthreads();
  }
  if (tid == 0) rowptr[n] = carry_s;
}

__global__ void scatter_kernel(const int* __restrict__ dstp, const int* __restrict__ rowptr,
                               int* __restrict__ fill, int* __restrict__ eid, int E) {
  for (int e = blockIdx.x * blockDim.x + threadIdx.x; e < E; e += gridDim.x * blockDim.x) {
    int d = dstp[e];
    int pos = atomicAdd(&fill[d], 1);
    eid[rowptr[d] + pos] = e;
  }
}

// ---------------- fp32 tiled GEMM ----------------
// C[M,NC] = A[M,K] @ W[K,NC] (+ bias).  EDGE_A: A row m = [cos(rel[m]*tw + tb), msg[m,:]]
template <int BM, int BN, int TM, int TN, int BK, bool EDGE_A>
__global__ void gemm_kernel(const float* __restrict__ A, const float* __restrict__ W,
                            const float* __restrict__ bias, float* __restrict__ C,
                            int M, int K, int NC,
                            const float* __restrict__ rel, const float* __restrict__ tw,
                            const float* __restrict__ tb, const float* __restrict__ msgp) {
  __shared__ float As[BK][BM + 4];   // +4 pad: conflict-free & 16B-aligned rows
  __shared__ float Bs[BK][BN];
  constexpr int TX = BN / TN;
  constexpr int TY = BM / TM;
  constexpr int NT = TX * TY;
  const int tx = threadIdx.x;
  const int ty = threadIdx.y;
  const int tid = ty * TX + tx;
  const int m0 = blockIdx.x * BM;
  const int n0 = blockIdx.y * BN;

  float acc[TM][TN];
#pragma unroll
  for (int i = 0; i < TM; ++i)
#pragma unroll
    for (int j = 0; j < TN; ++j) acc[i][j] = 0.f;

  for (int k0 = 0; k0 < K; k0 += BK) {
#pragma unroll
    for (int idx = tid; idx < BM * BK; idx += NT) {
      int r = idx / BK, kk = idx % BK;
      int gm = m0 + r, gk = k0 + kk;
      float v = 0.f;
      if (gm < M) {
        if constexpr (EDGE_A) {
          v = (gk < TDIM) ? cosf(rel[gm] * tw[gk] + tb[gk])
                          : msgp[(size_t)gm * MSGD + (gk - TDIM)];
        } else {
          v = A[(size_t)gm * K + gk];
        }
      }
      As[kk][r] = v;
    }
#pragma unroll
    for (int idx = tid; idx < BK * BN; idx += NT) {
      int kk = idx / BN, cc = idx % BN;
      Bs[kk][cc] = W[(size_t)(k0 + kk) * NC + n0 + cc];
    }
    __syncthreads();
#pragma unroll
    for (int kk = 0; kk < BK; ++kk) {
      float a[TM], b[TN];
#pragma unroll
      for (int i = 0; i < TM; ++i) a[i] = As[kk][ty * TM + i];
#pragma unroll
      for (int j = 0; j < TN; ++j) b[j] = Bs[kk][tx * TN + j];
#pragma unroll
      for (int i = 0; i < TM; ++i)
#pragma unroll
        for (int j = 0; j < TN; ++j) acc[i][j] += a[i] * b[j];
    }
    __syncthreads();
  }

#pragma unroll
  for (int i = 0; i < TM; ++i) {
    int gm = m0 + ty * TM + i;
    if (gm >= M) continue;
#pragma unroll
    for (int j = 0; j < TN; ++j) {
      int gn = n0 + tx * TN + j;
      float bv = bias ? bias[gn] : 0.f;
      C[(size_t)gm * NC + gn] = acc[i][j] + bv;
    }
  }
}

// ---------------- attention layer 1 (8 heads x 32, concat) ----------------
// block = 256 threads = one dst node; thread t -> (head t/32, channel t%32)
__global__ void attn1_kernel(const float* __restrict__ q1, const float* __restrict__ k1,
                             const float* __restrict__ v1, const float* __restrict__ e1,
                             const float* __restrict__ s1, const int* __restrict__ srcp,
                             const int* __restrict__ rowptr, const int* __restrict__ eid,
                             float* __restrict__ alpha, float* __restrict__ hout) {
  const int n = blockIdx.x;
  const int tid = threadIdx.x;
  const int hh = tid >> 5;
  const int beg = rowptr[n], end = rowptr[n + 1];
  const float qv = q1[(size_t)n * D + tid];
  float m = -INFINITY;
  for (int i = beg; i < end; ++i) {
    const int e = eid[i];
    const int s = srcp[e];
    float p = qv * (k1[(size_t)s * D + tid] + e1[(size_t)e * D + tid]);
#pragma unroll
    for (int off = 16; off; off >>= 1) p += __shfl_xor(p, off);
    p *= 0.17677669529663687f;  // 1/sqrt(32)
    if ((tid & 31) == 0) alpha[(size_t)e * H1 + hh] = p;
    m = fmaxf(m, p);
  }
  __syncthreads();
  float den = 0.f, acc = 0.f;
  for (int i = beg; i < end; ++i) {
    const int e = eid[i];
    const int s = srcp[e];
    float ex = expf(alpha[(size_t)e * H1 + hh] - m);
    den += ex;
    acc += ex * (v1[(size_t)s * D + tid] + e1[(size_t)e * D + tid]);
  }
  float o = acc / (den + 1e-16f) + s1[(size_t)n * D + tid];
  hout[(size_t)n * D + tid] = fmaxf(o, 0.f);
}

// ---------------- attention layer 2 (1 head x 32) ----------------
// block = 64 threads = one dst node (both 32-lane halves duplicate work; half stores)
__global__ void attn2_kernel(const float* __restrict__ q2, const float* __restrict__ k2,
                             const float* __restrict__ v2, const float* __restrict__ e2,
                             const float* __restrict__ s2, const int* __restrict__ srcp,
                             const int* __restrict__ rowptr, const int* __restrict__ eid,
                             float* __restrict__ alpha, float* __restrict__ outp) {
  const int n = blockIdx.x;
  const int tid = threadIdx.x;
  const int c = tid & 31;
  const int beg = rowptr[n], end = rowptr[n + 1];
  const float qv = q2[(size_t)n * CH + c];
  float m = -INFINITY;
  for (int i = beg; i < end; ++i) {
    const int e = eid[i];
    const int s = srcp[e];
    float p = qv * (k2[(size_t)s * CH + c] + e2[(size_t)e * CH + c]);
#pragma unroll
    for (int off = 16; off; off >>= 1) p += __shfl_xor(p, off);
    p *= 0.17677669529663687f;
    if (tid == 0) alpha[e] = p;
    m = fmaxf(m, p);
  }
  __syncthreads();
  float den = 0.f, acc = 0.f;
  for (int i = beg; i < end; ++i) {
    const int e = eid[i];
    const int s = srcp[e];
    float ex = expf(alpha[e] - m);
    den += ex;
    acc += ex * (v2[(size_t)s * CH + c] + e2[(size_t)e * CH + c]);
  }
  if (tid < 32) {
    float o = acc / (den + 1e-16f) + s2[(size_t)n * CH + c];
    outp[(size_t)n * CH + c] = fmaxf(o, 0.f);
  }
}

// ---------------- launcher ----------------
extern "C" void kernel_launch(void* const* d_in, const int* in_sizes, int n_in,
                              void* d_out, int out_size, void* d_ws, size_t ws_size,
                              hipStream_t stream) {
  const float* x   = (const float*)d_in[0];
  const float* lu  = (const float*)d_in[1];
  const int*   ei  = (const int*)d_in[2];
  const float* tt  = (const float*)d_in[3];
  const float* msg = (const float*)d_in[4];
  const float* tw  = (const float*)d_in[5];
  const float* tb  = (const float*)d_in[6];
  const float* Wq1 = (const float*)d_in[7];  const float* bq1 = (const float*)d_in[8];
  const float* Wk1 = (const float*)d_in[9];  const float* bk1 = (const float*)d_in[10];
  const float* Wv1 = (const float*)d_in[11]; const float* bv1 = (const float*)d_in[12];
  const float* We1 = (const float*)d_in[13];
  const float* Ws1 = (const float*)d_in[14]; const float* bs1 = (const float*)d_in[15];
  const float* Wq2 = (const float*)d_in[16]; const float* bq2 = (const float*)d_in[17];
  const float* Wk2 = (const float*)d_in[18]; const float* bk2 = (const float*)d_in[19];
  const float* Wv2 = (const float*)d_in[20]; const float* bv2 = (const float*)d_in[21];
  const float* We2 = (const float*)d_in[22];
  const float* Ws2 = (const float*)d_in[23]; const float* bs2 = (const float*)d_in[24];

  const int* srcp = ei;
  const int* dstp = ei + N_EDGES;

  // workspace carve-up (~248 MB total)
  char* p = (char*)d_ws;
  auto alloc = [&](size_t bytes) -> char* {
    char* r = p;
    p += (bytes + 255) & ~(size_t)255;
    return r;
  };
  float* rel    = (float*)alloc((size_t)N_EDGES * 4);
  float* q1     = (float*)alloc((size_t)N_NODES * D * 4);
  float* k1     = (float*)alloc((size_t)N_NODES * D * 4);
  float* v1     = (float*)alloc((size_t)N_NODES * D * 4);
  float* s1     = (float*)alloc((size_t)N_NODES * D * 4);
  float* e1     = (float*)alloc((size_t)N_EDGES * D * 4);
  float* alpha1 = (float*)alloc((size_t)N_EDGES * H1 * 4);
  float* h      = (float*)alloc((size_t)N_NODES * D * 4);
  float* q2     = (float*)alloc((size_t)N_NODES * CH * 4);
  float* k2     = (float*)alloc((size_t)N_NODES * CH * 4);
  float* v2     = (float*)alloc((size_t)N_NODES * CH * 4);
  float* s2     = (float*)alloc((size_t)N_NODES * CH * 4);
  float* e2     = (float*)alloc((size_t)N_EDGES * CH * 4);
  float* alpha2 = (float*)alloc((size_t)N_EDGES * 4);
  int*   deg    = (int*)alloc((size_t)N_NODES * 4);
  int*   fill   = (int*)alloc((size_t)N_NODES * 4);
  int*   rowptr = (int*)alloc((size_t)(N_NODES + 1) * 4);
  int*   eid    = (int*)alloc((size_t)N_EDGES * 4);

  float* outp = (float*)d_out;

  // CSR build + rel_t
  hipMemsetAsync(deg, 0, (size_t)N_NODES * 4, stream);
  hipMemsetAsync(fill, 0, (size_t)N_NODES * 4, stream);
  rel_kernel<<<ceildiv(N_EDGES, 256), 256, 0, stream>>>(lu, srcp, tt, rel, N_EDGES);
  count_kernel<<<ceildiv(N_EDGES, 256), 256, 0, stream>>>(dstp, deg, N_EDGES);
  scan_kernel<<<1, 1024, 0, stream>>>(deg, rowptr, N_NODES);
  scatter_kernel<<<ceildiv(N_EDGES, 256), 256, 0, stream>>>(dstp, rowptr, fill, eid, N_EDGES);

  dim3 blk(16, 16);
  // layer-1 node GEMMs: [N,256] @ [256,256]
  {
    dim3 grd(ceildiv(N_NODES, 64), D / 64);
    gemm_kernel<64, 64, 4, 4, 32, false><<<grd, blk, 0, stream>>>(x, Wq1, bq1, q1, N_NODES, D, D, nullptr, nullptr, nullptr, nullptr);
    gemm_kernel<64, 64, 4, 4, 32, false><<<grd, blk, 0, stream>>>(x, Wk1, bk1, k1, N_NODES, D, D, nullptr, nullptr, nullptr, nullptr);
    gemm_kernel<64, 64, 4, 4, 32, false><<<grd, blk, 0, stream>>>(x, Wv1, bv1, v1, N_NODES, D, D, nullptr, nullptr, nullptr, nullptr);
    gemm_kernel<64, 64, 4, 4, 32, false><<<grd, blk, 0, stream>>>(x, Ws1, bs1, s1, N_NODES, D, D, nullptr, nullptr, nullptr, nullptr);
  }
  // e1 = edge_attr @ We1  (edge_attr computed on the fly)
  {
    dim3 grd(N_EDGES / 64, D / 64);
    gemm_kernel<64, 64, 4, 4, 32, true><<<grd, blk, 0, stream>>>(nullptr, We1, nullptr, e1, N_EDGES, D, D, rel, tw, tb, msg);
  }
  // layer-1 attention -> h (relu(agg + skip))
  attn1_kernel<<<N_NODES, 256, 0, stream>>>(q1, k1, v1, e1, s1, srcp, rowptr, eid, alpha1, h);

  // layer-2 node GEMMs: [N,256] @ [256,32]
  {
    dim3 grd(ceildiv(N_NODES, 64), 1);
    gemm_kernel<64, 32, 4, 2, 32, false><<<grd, blk, 0, stream>>>(h, Wq2, bq2, q2, N_NODES, D, CH, nullptr, nullptr, nullptr, nullptr);
    gemm_kernel<64, 32, 4, 2, 32, false><<<grd, blk, 0, stream>>>(h, Wk2, bk2, k2, N_NODES, D, CH, nullptr, nullptr, nullptr, nullptr);
    gemm_kernel<64, 32, 4, 2, 32, false><<<grd, blk, 0, stream>>>(h, Wv2, bv2, v2, N_NODES, D, CH, nullptr, nullptr, nullptr, nullptr);
    gemm_kernel<64, 32, 4, 2, 32, false><<<grd, blk, 0, stream>>>(h, Ws2, bs2, s2, N_NODES, D, CH, nullptr, nullptr, nullptr, nullptr);
  }
  // e2 = edge_attr @ We2
  {
    dim3 grd(N_EDGES / 64, 1);
    gemm_kernel<64, 32, 4, 2, 32, true><<<grd, blk, 0, stream>>>(nullptr, We2, nullptr, e2, N_EDGES, D, CH, rel, tw, tb, msg);
  }
  // layer-2 attention -> output
  attn2_kernel<<<N_NODES, 64, 0, stream>>>(q2, k2, v2, e2, s2, srcp, rowptr, eid, alpha2, outp);
}

// Round 2
// 550.113 us; speedup vs baseline: 2.7541x; 2.7541x over previous
//
#include <hip/hip_runtime.h>
#include <math.h>

#define N_NODES 10000
#define N_EDGES 160000
#define D 256
#define H1 8
#define CH 32
#define TDIM 128
#define MSGD 128
#define RT1 157      // ceil(10000/64) row tiles for node matrices
#define RTE 2500     // 160000/64 row tiles for edge matrices

static inline int ceildiv(int a, int b) { return (a + b - 1) / b; }

typedef float f32x4 __attribute__((ext_vector_type(4)));
typedef short bf16x8 __attribute__((ext_vector_type(8)));

__device__ __forceinline__ unsigned short f2bf(float f) {
  unsigned int u = __builtin_bit_cast(unsigned int, f);
  u += 0x7FFFu + ((u >> 16) & 1u);   // RNE
  return (unsigned short)(u >> 16);
}
__device__ __forceinline__ float bf2f(unsigned short h) {
  unsigned int u = ((unsigned int)h) << 16;
  return __builtin_bit_cast(float, u);
}

// ---------------- prep: rel_t + CSR ----------------
__global__ void rel_kernel(const float* __restrict__ lu, const int* __restrict__ srcp,
                           const float* __restrict__ tt, float* __restrict__ rel, int E) {
  for (int i = blockIdx.x * blockDim.x + threadIdx.x; i < E; i += gridDim.x * blockDim.x)
    rel[i] = lu[srcp[i]] - tt[i];
}

__global__ void count_kernel(const int* __restrict__ dstp, int* __restrict__ deg, int E) {
  for (int i = blockIdx.x * blockDim.x + threadIdx.x; i < E; i += gridDim.x * blockDim.x)
    atomicAdd(&deg[dstp[i]], 1);
}

__global__ void scan_kernel(const int* __restrict__ deg, int* __restrict__ rowptr, int n) {
  __shared__ int sm[1024];
  __shared__ int carry_s;
  const int tid = threadIdx.x;
  if (tid == 0) carry_s = 0;
  __syncthreads();
  for (int base = 0; base < n; base += 1024) {
    int v = (base + tid < n) ? deg[base + tid] : 0;
    sm[tid] = v;
    __syncthreads();
    for (int off = 1; off < 1024; off <<= 1) {
      int y = 0;
      if (tid >= off) y = sm[tid - off];
      __syncthreads();
      sm[tid] += y;
      __syncthreads();
    }
    int incl = sm[tid];
    int carry = carry_s;
    if (base + tid < n) rowptr[base + tid] = carry + incl - v;
    __syncthreads();
    if (tid == 1023) carry_s = carry + incl;
    __syncthreads();
  }
  if (tid == 0) rowptr[n] = carry_s;
}

__global__ void scatter_kernel(const int* __restrict__ dstp, const int* __restrict__ rowptr,
                               int* __restrict__ fill, int* __restrict__ eid, int E) {
  for (int e = blockIdx.x * blockDim.x + threadIdx.x; e < E; e += gridDim.x * blockDim.x) {
    int d = dstp[e];
    int pos = atomicAdd(&fill[d], 1);
    eid[rowptr[d] + pos] = e;
  }
}

// ---------------- operand-layout converters ----------------
// A frag-linear layout (ushort units): addr(i,k) = rt*16384 + ks*2048 + rf*512 + (ir+16*kg)*8 + j
//   rt=i>>6, rf=(i>>4)&3, ir=i&15, ks=k>>5, kg=(k>>3)&3, j=k&7
// B frag-linear layout: addr(k,c) = (ks*NFtot + (c>>4))*512 + ((c&15)+16*kg)*8 + j

__global__ void conv_x_kernel(const float* __restrict__ x, unsigned short* __restrict__ xa,
                              int M, int RT) {
  int t = blockIdx.x * blockDim.x + threadIdx.x;
  if (t >= RT * 64 * 32) return;
  int i = t >> 5, k8 = t & 31;
  int k = k8 * 8;
  union { uint4 q; unsigned short s[8]; } u;
  if (i < M) {
    const float4* px = (const float4*)(x + (size_t)i * 256 + k);
    float4 f0 = px[0], f1 = px[1];
    u.s[0]=f2bf(f0.x); u.s[1]=f2bf(f0.y); u.s[2]=f2bf(f0.z); u.s[3]=f2bf(f0.w);
    u.s[4]=f2bf(f1.x); u.s[5]=f2bf(f1.y); u.s[6]=f2bf(f1.z); u.s[7]=f2bf(f1.w);
  } else {
    u.q = make_uint4(0,0,0,0);
  }
  int rt=i>>6, rf=(i>>4)&3, ir=i&15, ks=k8>>2, kg=k8&3;
  *(uint4*)&xa[(size_t)rt*16384 + ks*2048 + rf*512 + (ir+16*kg)*8] = u.q;
}

__global__ void conv_w_kernel(const float* __restrict__ W, unsigned short* __restrict__ out,
                              int Nin, int n_off, int NFtot) {
  int t = blockIdx.x * blockDim.x + threadIdx.x;
  if (t >= 256 * Nin) return;
  int k = t / Nin, c = t % Nin;
  int gc = n_off + c;
  int ks=k>>5, kg=(k>>3)&3, j=k&7, nf=gc>>4, ic=gc&15;
  out[(size_t)(ks*NFtot+nf)*512 + (ic+16*kg)*8 + j] = f2bf(W[(size_t)k*Nin + c]);
}

__global__ void concat4_kernel(float* __restrict__ out, const float* __restrict__ a,
                               const float* __restrict__ b, const float* __restrict__ c,
                               const float* __restrict__ d, int L) {
  int t = blockIdx.x * blockDim.x + threadIdx.x;
  if (t >= 4 * L) return;
  float v;
  if (t < L) v = a[t];
  else if (t < 2*L) v = b[t - L];
  else if (t < 3*L) v = c[t - 2*L];
  else v = d[t - 3*L];
  out[t] = v;
}

// edge_attr in SORTED order, frag layout; also emit src_sorted
__global__ void build_ea_kernel(const float* __restrict__ rel, const float* __restrict__ tw,
                                const float* __restrict__ tb, const float* __restrict__ msg,
                                const int* __restrict__ eid, const int* __restrict__ srcp,
                                unsigned short* __restrict__ ea, int* __restrict__ srcs) {
  int t = blockIdx.x * blockDim.x + threadIdx.x;
  if (t >= N_EDGES * 32) return;
  int i = t >> 5, k8 = t & 31;
  int e = eid[i];
  if (k8 == 0) srcs[i] = srcp[e];
  union { uint4 q; unsigned short s[8]; } u;
  if (k8 < 16) {
    float r = rel[e];
    int k = k8 * 8;
#pragma unroll
    for (int j = 0; j < 8; ++j) u.s[j] = f2bf(__cosf(r * tw[k+j] + tb[k+j]));
  } else {
    int k = (k8 - 16) * 8;
    const float4* pm = (const float4*)(msg + (size_t)e * MSGD + k);
    float4 f0 = pm[0], f1 = pm[1];
    u.s[0]=f2bf(f0.x); u.s[1]=f2bf(f0.y); u.s[2]=f2bf(f0.z); u.s[3]=f2bf(f0.w);
    u.s[4]=f2bf(f1.x); u.s[5]=f2bf(f1.y); u.s[6]=f2bf(f1.z); u.s[7]=f2bf(f1.w);
  }
  int rt=i>>6, rf=(i>>4)&3, ir=i&15, ks=k8>>2, kg=k8&3;
  *(uint4*)&ea[(size_t)rt*16384 + ks*2048 + rf*512 + (ir+16*kg)*8] = u.q;
}

// ---------------- MFMA GEMM ----------------
// Wave tile 64x64 (4x4 frags). Block = 4 waves in WRW x (4/WRW) grid.
// K = 256 fixed (8 steps of 32). A,B pre-fragmented bf16. C row-major f32 or bf16.
template <int WRW, bool OUTF32>
__global__ __launch_bounds__(256)
void gemm_mfma(const unsigned short* __restrict__ A, const unsigned short* __restrict__ B,
               const float* __restrict__ bias, void* __restrict__ Cout,
               int RT, int M, int NFtot, int Creal, int Cstride) {
  constexpr int WCW = 4 / WRW;
  constexpr int ACH = WRW * 256;        // A 16B-chunks per K-step
  constexpr int BCH = WCW * 1024 / 4;   // = WCW*256 chunks
  constexpr int CH_TOT = ACH + BCH;
  constexpr int PER_T = CH_TOT / 256;
  __shared__ uint4 lds[CH_TOT];

  const int tid = threadIdx.x;
  const int wid = tid >> 6, lane = tid & 63;
  const int wr = (WRW == 1) ? 0 : ((WRW == 4) ? wid : (wid >> 1));
  const int wc = (WRW == 1) ? wid : ((WRW == 4) ? 0 : (wid & 1));
  const int rt0 = blockIdx.x * WRW;
  const int n0f = blockIdx.y * (WCW * 4);

  auto src_of = [&](int ks, int c) -> const uint4* {
    if (c < ACH) {
      int rt = rt0 + (c >> 8);
      if (rt >= RT) rt = RT - 1;
      return (const uint4*)(A + (size_t)rt * 16384 + ks * 2048 + (size_t)(c & 255) * 8);
    }
    int cb = c - ACH;
    return (const uint4*)(B + ((size_t)ks * NFtot + n0f) * 512 + (size_t)cb * 8);
  };

  uint4 st[PER_T];
#pragma unroll
  for (int p = 0; p < PER_T; ++p) st[p] = *src_of(0, tid + p * 256);

  f32x4 acc[4][4];
#pragma unroll
  for (int i = 0; i < 4; ++i)
#pragma unroll
    for (int j = 0; j < 4; ++j) acc[i][j] = (f32x4){0.f, 0.f, 0.f, 0.f};

  for (int ks = 0; ks < 8; ++ks) {
    __syncthreads();   // LDS free (prev reads done)
#pragma unroll
    for (int p = 0; p < PER_T; ++p) lds[tid + p * 256] = st[p];
    if (ks < 7) {
#pragma unroll
      for (int p = 0; p < PER_T; ++p) st[p] = *src_of(ks + 1, tid + p * 256);
    }
    __syncthreads();   // LDS ready
    bf16x8 a[4], b[4];
#pragma unroll
    for (int rf = 0; rf < 4; ++rf) a[rf] = *(const bf16x8*)&lds[(wr * 4 + rf) * 64 + lane];
#pragma unroll
    for (int cf = 0; cf < 4; ++cf) b[cf] = *(const bf16x8*)&lds[ACH + (wc * 4 + cf) * 64 + lane];
#pragma unroll
    for (int rf = 0; rf < 4; ++rf)
#pragma unroll
      for (int cf = 0; cf < 4; ++cf)
        acc[rf][cf] = __builtin_amdgcn_mfma_f32_16x16x32_bf16(a[rf], b[cf], acc[rf][cf], 0, 0, 0);
  }

  // epilogue: C/D layout col=lane&15, row=(lane>>4)*4+reg
  const int rtg = rt0 + wr;
  const int row0 = rtg * 64 + ((lane >> 4) * 4);
  const int colbase = blockIdx.y * WCW * 64 + wc * 64 + (lane & 15);
#pragma unroll
  for (int cf = 0; cf < 4; ++cf) {
    int c = colbase + cf * 16;
    if (c >= Creal) continue;
    float bv = bias ? bias[c] : 0.f;
#pragma unroll
    for (int rf = 0; rf < 4; ++rf) {
#pragma unroll
      for (int j = 0; j < 4; ++j) {
        int r = row0 + rf * 16 + j;
        if (r < M) {
          float v = acc[rf][cf][j] + bv;
          if (OUTF32) ((float*)Cout)[(size_t)r * Cstride + c] = v;
          else ((unsigned short*)Cout)[(size_t)r * Cstride + c] = f2bf(v);
        }
      }
    }
  }
}

// ---------------- attention layer 1 (8 heads x 32, concat) ----------------
// block = 256 threads = one dst node; thread t -> (head t/32, channel t%32)
// qkvs f32 row-major [n][1024]: q 0-255, k 256-511, v 512-767, skip 768-1023
// e1b bf16 [i][256] in sorted edge order; output h written in A-frag layout (bf16)
__global__ void attn1_kernel(const float* __restrict__ qkvs, const unsigned short* __restrict__ e1b,
                             const int* __restrict__ srcs, const int* __restrict__ rowptr,
                             float* __restrict__ alpha, unsigned short* __restrict__ ha) {
  const int n = blockIdx.x;
  const int tid = threadIdx.x;
  const int hh = tid >> 5;
  const int beg = rowptr[n], end = rowptr[n + 1];
  const float qv = qkvs[(size_t)n * 1024 + tid];
  float m = -INFINITY;
  for (int i = beg; i < end; ++i) {
    const int s = srcs[i];
    float p = qv * (qkvs[(size_t)s * 1024 + 256 + tid] + bf2f(e1b[(size_t)i * 256 + tid]));
#pragma unroll
    for (int off = 16; off; off >>= 1) p += __shfl_xor(p, off);
    p *= 0.17677669529663687f;  // 1/sqrt(32)
    if ((tid & 31) == 0) alpha[(size_t)i * H1 + hh] = p;
    m = fmaxf(m, p);
  }
  __syncthreads();
  float den = 0.f, acc = 0.f;
  for (int i = beg; i < end; ++i) {
    const int s = srcs[i];
    float ex = __expf(alpha[(size_t)i * H1 + hh] - m);
    den += ex;
    acc += ex * (qkvs[(size_t)s * 1024 + 512 + tid] + bf2f(e1b[(size_t)i * 256 + tid]));
  }
  float o = acc / (den + 1e-16f) + qkvs[(size_t)n * 1024 + 768 + tid];
  o = fmaxf(o, 0.f);
  int rt=n>>6, rf=(n>>4)&3, ir=n&15, ks=tid>>5, kg=(tid>>3)&3, j=tid&7;
  ha[(size_t)rt*16384 + ks*2048 + rf*512 + (ir+16*kg)*8 + j] = f2bf(o);
}

// ---------------- attention layer 2 (1 head x 32) ----------------
// qkvs2 f32 [n][128]: q 0-31, k 32-63, v 64-95, skip 96-127 ; e2b bf16 [i][32]
__global__ void attn2_kernel(const float* __restrict__ qkvs2, const unsigned short* __restrict__ e2b,
                             const int* __restrict__ srcs, const int* __restrict__ rowptr,
                             float* __restrict__ alpha, float* __restrict__ outp) {
  const int n = blockIdx.x;
  const int tid = threadIdx.x;
  const int c = tid & 31;
  const int beg = rowptr[n], end = rowptr[n + 1];
  const float qv = qkvs2[(size_t)n * 128 + c];
  float m = -INFINITY;
  for (int i = beg; i < end; ++i) {
    const int s = srcs[i];
    float p = qv * (qkvs2[(size_t)s * 128 + 32 + c] + bf2f(e2b[(size_t)i * 32 + c]));
#pragma unroll
    for (int off = 16; off; off >>= 1) p += __shfl_xor(p, off);
    p *= 0.17677669529663687f;
    if (tid == 0) alpha[i] = p;
    m = fmaxf(m, p);
  }
  __syncthreads();
  float den = 0.f, acc = 0.f;
  for (int i = beg; i < end; ++i) {
    const int s = srcs[i];
    float ex = __expf(alpha[i] - m);
    den += ex;
    acc += ex * (qkvs2[(size_t)s * 128 + 64 + c] + bf2f(e2b[(size_t)i * 32 + c]));
  }
  if (tid < 32) {
    float o = acc / (den + 1e-16f) + qkvs2[(size_t)n * 128 + 96 + c];
    outp[(size_t)n * CH + c] = fmaxf(o, 0.f);
  }
}

// ---------------- launcher ----------------
extern "C" void kernel_launch(void* const* d_in, const int* in_sizes, int n_in,
                              void* d_out, int out_size, void* d_ws, size_t ws_size,
                              hipStream_t stream) {
  const float* x   = (const float*)d_in[0];
  const float* lu  = (const float*)d_in[1];
  const int*   ei  = (const int*)d_in[2];
  const float* tt  = (const float*)d_in[3];
  const float* msg = (const float*)d_in[4];
  const float* tw  = (const float*)d_in[5];
  const float* tb  = (const float*)d_in[6];
  const float* Wq1 = (const float*)d_in[7];  const float* bq1 = (const float*)d_in[8];
  const float* Wk1 = (const float*)d_in[9];  const float* bk1 = (const float*)d_in[10];
  const float* Wv1 = (const float*)d_in[11]; const float* bv1 = (const float*)d_in[12];
  const float* We1 = (const float*)d_in[13];
  const float* Ws1 = (const float*)d_in[14]; const float* bs1 = (const float*)d_in[15];
  const float* Wq2 = (const float*)d_in[16]; const float* bq2 = (const float*)d_in[17];
  const float* Wk2 = (const float*)d_in[18]; const float* bk2 = (const float*)d_in[19];
  const float* Wv2 = (const float*)d_in[20]; const float* bv2 = (const float*)d_in[21];
  const float* We2 = (const float*)d_in[22];
  const float* Ws2 = (const float*)d_in[23]; const float* bs2 = (const float*)d_in[24];

  const int* srcp = ei;
  const int* dstp = ei + N_EDGES;

  char* p = (char*)d_ws;
  auto alloc = [&](size_t bytes) -> char* {
    char* r = p;
    p += (bytes + 255) & ~(size_t)255;
    return r;
  };
  float* rel    = (float*)alloc((size_t)N_EDGES * 4);
  int*   deg    = (int*)alloc((size_t)N_NODES * 4);
  int*   fill   = (int*)alloc((size_t)N_NODES * 4);
  int*   rowptr = (int*)alloc((size_t)(N_NODES + 1) * 4);
  int*   eid    = (int*)alloc((size_t)N_EDGES * 4);
  int*   srcs   = (int*)alloc((size_t)N_EDGES * 4);
  unsigned short* xa    = (unsigned short*)alloc((size_t)RT1 * 32768);
  unsigned short* W1f   = (unsigned short*)alloc((size_t)8 * 64 * 1024);  // 1024 cols
  unsigned short* We1f  = (unsigned short*)alloc((size_t)8 * 16 * 1024);  // 256 cols
  unsigned short* W2f   = (unsigned short*)alloc((size_t)8 * 8 * 1024);   // 128 cols
  unsigned short* We2f  = (unsigned short*)alloc((size_t)8 * 4 * 1024);   // 64 cols (32 real + pad)
  float* bcat1  = (float*)alloc(1024 * 4);
  float* bcat2  = (float*)alloc(128 * 4);
  unsigned short* ea    = (unsigned short*)alloc((size_t)RTE * 32768);    // 82 MB
  float* qkvs   = (float*)alloc((size_t)N_NODES * 1024 * 4);              // 41 MB
  unsigned short* e1b   = (unsigned short*)alloc((size_t)N_EDGES * 256 * 2);  // 82 MB
  float* alpha1 = (float*)alloc((size_t)N_EDGES * H1 * 4);
  unsigned short* ha    = (unsigned short*)alloc((size_t)RT1 * 32768);
  float* qkvs2  = (float*)alloc((size_t)N_NODES * 128 * 4);
  unsigned short* e2b   = (unsigned short*)alloc((size_t)N_EDGES * 32 * 2);
  float* alpha2 = (float*)alloc((size_t)N_EDGES * 4);
  float* outp   = (float*)d_out;

  hipMemsetAsync(deg, 0, (size_t)N_NODES * 4, stream);
  hipMemsetAsync(fill, 0, (size_t)N_NODES * 4, stream);
  hipMemsetAsync(We2f, 0, (size_t)8 * 4 * 1024 * 2, stream);
  hipMemsetAsync(ha, 0, (size_t)RT1 * 32768, stream);   // zero pad rows for node2 GEMM

  rel_kernel<<<625, 256, 0, stream>>>(lu, srcp, tt, rel, N_EDGES);
  count_kernel<<<625, 256, 0, stream>>>(dstp, deg, N_EDGES);
  scan_kernel<<<1, 1024, 0, stream>>>(deg, rowptr, N_NODES);
  scatter_kernel<<<625, 256, 0, stream>>>(dstp, rowptr, fill, eid, N_EDGES);

  // weight / input conversions to frag layout
  conv_x_kernel<<<ceildiv(RT1 * 64 * 32, 256), 256, 0, stream>>>(x, xa, N_NODES, RT1);
  conv_w_kernel<<<256, 256, 0, stream>>>(Wq1, W1f, 256, 0,   64);
  conv_w_kernel<<<256, 256, 0, stream>>>(Wk1, W1f, 256, 256, 64);
  conv_w_kernel<<<256, 256, 0, stream>>>(Wv1, W1f, 256, 512, 64);
  conv_w_kernel<<<256, 256, 0, stream>>>(Ws1, W1f, 256, 768, 64);
  conv_w_kernel<<<256, 256, 0, stream>>>(We1, We1f, 256, 0, 16);
  conv_w_kernel<<<32, 256, 0, stream>>>(Wq2, W2f, 32, 0,  8);
  conv_w_kernel<<<32, 256, 0, stream>>>(Wk2, W2f, 32, 32, 8);
  conv_w_kernel<<<32, 256, 0, stream>>>(Wv2, W2f, 32, 64, 8);
  conv_w_kernel<<<32, 256, 0, stream>>>(Ws2, W2f, 32, 96, 8);
  conv_w_kernel<<<32, 256, 0, stream>>>(We2, We2f, 32, 0, 4);
  concat4_kernel<<<4, 256, 0, stream>>>(bcat1, bq1, bk1, bv1, bs1, 256);
  concat4_kernel<<<1, 256, 0, stream>>>(bcat2, bq2, bk2, bv2, bs2, 32);

  // edge_attr (sorted, frag layout) + src_sorted
  build_ea_kernel<<<ceildiv(N_EDGES * 32, 256), 256, 0, stream>>>(rel, tw, tb, msg, eid, srcp, ea, srcs);

  // layer-1 GEMMs
  {
    dim3 g1(RT1, 4);
    gemm_mfma<1, true><<<g1, 256, 0, stream>>>(xa, W1f, bcat1, qkvs, RT1, N_NODES, 64, 1024, 1024);
    dim3 ge(RTE, 1);
    gemm_mfma<1, false><<<ge, 256, 0, stream>>>(ea, We1f, nullptr, e1b, RTE, N_EDGES, 16, 256, 256);
  }
  attn1_kernel<<<N_NODES, 256, 0, stream>>>(qkvs, e1b, srcs, rowptr, alpha1, ha);

  // layer-2 GEMMs
  {
    dim3 g2(ceildiv(RT1, 2), 1);
    gemm_mfma<2, true><<<g2, 256, 0, stream>>>(ha, W2f, bcat2, qkvs2, RT1, N_NODES, 8, 128, 128);
    dim3 ge2(RTE / 4, 1);
    gemm_mfma<4, false><<<ge2, 256, 0, stream>>>(ea, We2f, nullptr, e2b, RTE, N_EDGES, 4, 32, 32);
  }
  attn2_kernel<<<N_NODES, 64, 0, stream>>>(qkvs2, e2b, srcs, rowptr, alpha2, outp);
}

// Round 3
// 475.176 us; speedup vs baseline: 3.1884x; 1.1577x over previous
//
#include <hip/hip_runtime.h>
#include <math.h>

#define N_NODES 10000
#define N_EDGES 160000
#define D 256
#define H1 8
#define CH 32
#define TDIM 128
#define MSGD 128
#define RT1 157      // ceil(10000/64) row tiles for node matrices
#define RTE 2500     // 160000/64 row tiles for edge matrices

static inline int ceildiv(int a, int b) { return (a + b - 1) / b; }

typedef float f32x4 __attribute__((ext_vector_type(4)));
typedef short bf16x8 __attribute__((ext_vector_type(8)));

__device__ __forceinline__ unsigned short f2bf(float f) {
  unsigned int u = __builtin_bit_cast(unsigned int, f);
  u += 0x7FFFu + ((u >> 16) & 1u);   // RNE
  return (unsigned short)(u >> 16);
}
__device__ __forceinline__ float bf2f(unsigned short h) {
  unsigned int u = ((unsigned int)h) << 16;
  return __builtin_bit_cast(float, u);
}

// ---------------- prep: rel_t + CSR ----------------
__global__ void rel_kernel(const float* __restrict__ lu, const int* __restrict__ srcp,
                           const float* __restrict__ tt, float* __restrict__ rel, int E) {
  for (int i = blockIdx.x * blockDim.x + threadIdx.x; i < E; i += gridDim.x * blockDim.x)
    rel[i] = lu[srcp[i]] - tt[i];
}

__global__ void count_kernel(const int* __restrict__ dstp, int* __restrict__ deg, int E) {
  for (int i = blockIdx.x * blockDim.x + threadIdx.x; i < E; i += gridDim.x * blockDim.x)
    atomicAdd(&deg[dstp[i]], 1);
}

__global__ void scan_kernel(const int* __restrict__ deg, int* __restrict__ rowptr, int n) {
  __shared__ int sm[1024];
  __shared__ int carry_s;
  const int tid = threadIdx.x;
  if (tid == 0) carry_s = 0;
  __syncthreads();
  for (int base = 0; base < n; base += 1024) {
    int v = (base + tid < n) ? deg[base + tid] : 0;
    sm[tid] = v;
    __syncthreads();
    for (int off = 1; off < 1024; off <<= 1) {
      int y = 0;
      if (tid >= off) y = sm[tid - off];
      __syncthreads();
      sm[tid] += y;
      __syncthreads();
    }
    int incl = sm[tid];
    int carry = carry_s;
    if (base + tid < n) rowptr[base + tid] = carry + incl - v;
    __syncthreads();
    if (tid == 1023) carry_s = carry + incl;
    __syncthreads();
  }
  if (tid == 0) rowptr[n] = carry_s;
}

__global__ void scatter_kernel(const int* __restrict__ dstp, const int* __restrict__ rowptr,
                               int* __restrict__ fill, int* __restrict__ eid, int E) {
  for (int e = blockIdx.x * blockDim.x + threadIdx.x; e < E; e += gridDim.x * blockDim.x) {
    int d = dstp[e];
    int pos = atomicAdd(&fill[d], 1);
    eid[rowptr[d] + pos] = e;
  }
}

// ---------------- operand-layout converters ----------------
// A frag-linear layout (ushort units): addr(i,k) = rt*16384 + ks*2048 + rf*512 + (ir+16*kg)*8 + j
//   rt=i>>6, rf=(i>>4)&3, ir=i&15, ks=k>>5, kg=(k>>3)&3, j=k&7
// B frag-linear layout: addr(k,c) = (ks*NFtot + (c>>4))*512 + ((c&15)+16*kg)*8 + j

__global__ void conv_x_kernel(const float* __restrict__ x, unsigned short* __restrict__ xa,
                              int M, int RT) {
  int t = blockIdx.x * blockDim.x + threadIdx.x;
  if (t >= RT * 64 * 32) return;
  int i = t >> 5, k8 = t & 31;
  int k = k8 * 8;
  union { uint4 q; unsigned short s[8]; } u;
  if (i < M) {
    const float4* px = (const float4*)(x + (size_t)i * 256 + k);
    float4 f0 = px[0], f1 = px[1];
    u.s[0]=f2bf(f0.x); u.s[1]=f2bf(f0.y); u.s[2]=f2bf(f0.z); u.s[3]=f2bf(f0.w);
    u.s[4]=f2bf(f1.x); u.s[5]=f2bf(f1.y); u.s[6]=f2bf(f1.z); u.s[7]=f2bf(f1.w);
  } else {
    u.q = make_uint4(0,0,0,0);
  }
  int rt=i>>6, rf=(i>>4)&3, ir=i&15, ks=k8>>2, kg=k8&3;
  *(uint4*)&xa[(size_t)rt*16384 + ks*2048 + rf*512 + (ir+16*kg)*8] = u.q;
}

__global__ void conv_w_kernel(const float* __restrict__ W, unsigned short* __restrict__ out,
                              int Nin, int n_off, int NFtot) {
  int t = blockIdx.x * blockDim.x + threadIdx.x;
  if (t >= 256 * Nin) return;
  int k = t / Nin, c = t % Nin;
  int gc = n_off + c;
  int ks=k>>5, kg=(k>>3)&3, j=k&7, nf=gc>>4, ic=gc&15;
  out[(size_t)(ks*NFtot+nf)*512 + (ic+16*kg)*8 + j] = f2bf(W[(size_t)k*Nin + c]);
}

__global__ void concat4_kernel(float* __restrict__ out, const float* __restrict__ a,
                               const float* __restrict__ b, const float* __restrict__ c,
                               const float* __restrict__ d, int L) {
  int t = blockIdx.x * blockDim.x + threadIdx.x;
  if (t >= 4 * L) return;
  float v;
  if (t < L) v = a[t];
  else if (t < 2*L) v = b[t - L];
  else if (t < 3*L) v = c[t - 2*L];
  else v = d[t - 3*L];
  out[t] = v;
}

// edge_attr in SORTED order, frag layout; also emit src_sorted
__global__ void build_ea_kernel(const float* __restrict__ rel, const float* __restrict__ tw,
                                const float* __restrict__ tb, const float* __restrict__ msg,
                                const int* __restrict__ eid, const int* __restrict__ srcp,
                                unsigned short* __restrict__ ea, int* __restrict__ srcs) {
  int t = blockIdx.x * blockDim.x + threadIdx.x;
  if (t >= N_EDGES * 32) return;
  int i = t >> 5, k8 = t & 31;
  int e = eid[i];
  if (k8 == 0) srcs[i] = srcp[e];
  union { uint4 q; unsigned short s[8]; } u;
  if (k8 < 16) {
    float r = rel[e];
    int k = k8 * 8;
#pragma unroll
    for (int j = 0; j < 8; ++j) u.s[j] = f2bf(__cosf(r * tw[k+j] + tb[k+j]));
  } else {
    int k = (k8 - 16) * 8;
    const float4* pm = (const float4*)(msg + (size_t)e * MSGD + k);
    float4 f0 = pm[0], f1 = pm[1];
    u.s[0]=f2bf(f0.x); u.s[1]=f2bf(f0.y); u.s[2]=f2bf(f0.z); u.s[3]=f2bf(f0.w);
    u.s[4]=f2bf(f1.x); u.s[5]=f2bf(f1.y); u.s[6]=f2bf(f1.z); u.s[7]=f2bf(f1.w);
  }
  int rt=i>>6, rf=(i>>4)&3, ir=i&15, ks=k8>>2, kg=k8&3;
  *(uint4*)&ea[(size_t)rt*16384 + ks*2048 + rf*512 + (ir+16*kg)*8] = u.q;
}

// ---------------- MFMA GEMM ----------------
// Wave tile 64x64 (4x4 frags). Block = 4 waves in WRW x (4/WRW) grid.
// K = 256 fixed (8 steps of 32). A,B pre-fragmented bf16.
// OUTF32: direct f32 row-major stores (64B-contiguous lane groups, coalesced).
// !OUTF32: bf16 out via LDS C-tile transpose -> dwordx4 row-major stores
//          (direct 2B stores caused 5.2x HBM write amplification in R2).
template <int WRW, bool OUTF32>
__global__ __launch_bounds__(256)
void gemm_mfma(const unsigned short* __restrict__ A, const unsigned short* __restrict__ B,
               const float* __restrict__ bias, void* __restrict__ Cout,
               int RT, int M, int NFtot, int Creal, int Cstride) {
  constexpr int WCW = 4 / WRW;
  constexpr int ACH = WRW * 256;        // A 16B-chunks per K-step
  constexpr int BCH = WCW * 256;        // B 16B-chunks per K-step
  constexpr int CH_TOT = ACH + BCH;
  constexpr int PER_T = CH_TOT / 256;
  constexpr int ROWS = WRW * 64;
  constexpr int COLS = WCW * 64;
  constexpr int CSTR = COLS + 8;        // ushort stride: 16B-aligned rows, bank-spread
  constexpr int STAGE_B = CH_TOT * 16;
  constexpr int CTILE_B = OUTF32 ? 0 : ROWS * CSTR * 2;
  constexpr int LDS_B = (STAGE_B > CTILE_B) ? STAGE_B : CTILE_B;
  __shared__ char ldsraw[LDS_B];
  uint4* lds = (uint4*)ldsraw;

  const int tid = threadIdx.x;
  const int wid = tid >> 6, lane = tid & 63;
  const int wr = (WRW == 1) ? 0 : ((WRW == 4) ? wid : (wid >> 1));
  const int wc = (WRW == 1) ? wid : ((WRW == 4) ? 0 : (wid & 1));
  const int rt0 = blockIdx.x * WRW;
  const int n0f = blockIdx.y * (WCW * 4);

  auto src_of = [&](int ks, int c) -> const uint4* {
    if (c < ACH) {
      int rt = rt0 + (c >> 8);
      if (rt >= RT) rt = RT - 1;
      return (const uint4*)(A + (size_t)rt * 16384 + ks * 2048 + (size_t)(c & 255) * 8);
    }
    int cb = c - ACH;
    return (const uint4*)(B + ((size_t)ks * NFtot + n0f) * 512 + (size_t)cb * 8);
  };

  uint4 st[PER_T];
#pragma unroll
  for (int p = 0; p < PER_T; ++p) st[p] = *src_of(0, tid + p * 256);

  f32x4 acc[4][4];
#pragma unroll
  for (int i = 0; i < 4; ++i)
#pragma unroll
    for (int j = 0; j < 4; ++j) acc[i][j] = (f32x4){0.f, 0.f, 0.f, 0.f};

  for (int ks = 0; ks < 8; ++ks) {
    __syncthreads();   // LDS free (prev reads done)
#pragma unroll
    for (int p = 0; p < PER_T; ++p) lds[tid + p * 256] = st[p];
    if (ks < 7) {
#pragma unroll
      for (int p = 0; p < PER_T; ++p) st[p] = *src_of(ks + 1, tid + p * 256);
    }
    __syncthreads();   // LDS ready
    bf16x8 a[4], b[4];
#pragma unroll
    for (int rf = 0; rf < 4; ++rf) a[rf] = *(const bf16x8*)&lds[(wr * 4 + rf) * 64 + lane];
#pragma unroll
    for (int cf = 0; cf < 4; ++cf) b[cf] = *(const bf16x8*)&lds[ACH + (wc * 4 + cf) * 64 + lane];
#pragma unroll
    for (int rf = 0; rf < 4; ++rf)
#pragma unroll
      for (int cf = 0; cf < 4; ++cf)
        acc[rf][cf] = __builtin_amdgcn_mfma_f32_16x16x32_bf16(a[rf], b[cf], acc[rf][cf], 0, 0, 0);
  }

  // epilogue: C/D layout col=lane&15, row=(lane>>4)*4+reg
  if constexpr (OUTF32) {
    const int row0 = (rt0 + wr) * 64 + ((lane >> 4) * 4);
    const int colbase = blockIdx.y * WCW * 64 + wc * 64 + (lane & 15);
#pragma unroll
    for (int cf = 0; cf < 4; ++cf) {
      int c = colbase + cf * 16;
      if (c >= Creal) continue;
      float bv = bias ? bias[c] : 0.f;
#pragma unroll
      for (int rf = 0; rf < 4; ++rf) {
#pragma unroll
        for (int j = 0; j < 4; ++j) {
          int r = row0 + rf * 16 + j;
          if (r < M) ((float*)Cout)[(size_t)r * Cstride + c] = acc[rf][cf][j] + bv;
        }
      }
    }
  } else {
    // bf16 path: stage tile in LDS, then coalesced row-major dwordx4 stores
    __syncthreads();   // staging reads of last K-step done; safe to overwrite LDS
    unsigned short* cl = (unsigned short*)ldsraw;
    const int r0 = wr * 64 + ((lane >> 4) * 4);
    const int c0 = wc * 64 + (lane & 15);
#pragma unroll
    for (int rf = 0; rf < 4; ++rf)
#pragma unroll
      for (int cf = 0; cf < 4; ++cf)
#pragma unroll
        for (int j = 0; j < 4; ++j)
          cl[(size_t)(r0 + rf * 16 + j) * CSTR + c0 + cf * 16] = f2bf(acc[rf][cf][j]);
    __syncthreads();
    const int CPC = Creal >> 3;          // 8-ushort chunks per output row
    const int total = ROWS * CPC;
    const int gc0 = blockIdx.y * (WCW * 64);
    for (int id = tid; id < total; id += 256) {
      int row = id / CPC, colc = (id - row * CPC) * 8;
      int gr = rt0 * 64 + row;
      if (gr < M) {
        uint4 v = *(const uint4*)&cl[(size_t)row * CSTR + colc];
        *(uint4*)&((unsigned short*)Cout)[(size_t)gr * Cstride + gc0 + colc] = v;
      }
    }
  }
}

// ---------------- attention layer 1 (8 heads x 32, concat) ----------------
// block = 256 threads = one dst node; thread t -> (head t/32, channel t%32)
// qkvs f32 row-major [n][1024]: q 0-255, k 256-511, v 512-767, skip 768-1023
// e1b bf16 [i][256] sorted edge order; ONLINE softmax (single pass, no alpha buf)
// output h written in A-frag layout (bf16)
__global__ void attn1_kernel(const float* __restrict__ qkvs, const unsigned short* __restrict__ e1b,
                             const int* __restrict__ srcs, const int* __restrict__ rowptr,
                             unsigned short* __restrict__ ha) {
  const int n = blockIdx.x;
  const int tid = threadIdx.x;
  const int beg = rowptr[n], end = rowptr[n + 1];
  const float qv = qkvs[(size_t)n * 1024 + tid];
  float m = -INFINITY, den = 0.f, acc = 0.f;
  for (int i = beg; i < end; ++i) {
    const int s = srcs[i];
    const float ev = bf2f(e1b[(size_t)i * 256 + tid]);
    const float kv = qkvs[(size_t)s * 1024 + 256 + tid] + ev;
    const float vv = qkvs[(size_t)s * 1024 + 512 + tid] + ev;
    float p = qv * kv;
#pragma unroll
    for (int off = 16; off; off >>= 1) p += __shfl_xor(p, off);
    p *= 0.17677669529663687f;  // 1/sqrt(32)
    const float mn = fmaxf(m, p);
    const float scale = __expf(m - mn);   // first iter: exp(-inf)=0
    const float w = __expf(p - mn);
    den = den * scale + w;
    acc = acc * scale + w * vv;
    m = mn;
  }
  float o = acc / (den + 1e-16f) + qkvs[(size_t)n * 1024 + 768 + tid];
  o = fmaxf(o, 0.f);
  int rt=n>>6, rf=(n>>4)&3, ir=n&15, ks=tid>>5, kg=(tid>>3)&3, j=tid&7;
  ha[(size_t)rt*16384 + ks*2048 + rf*512 + (ir+16*kg)*8 + j] = f2bf(o);
}

// ---------------- attention layer 2 (1 head x 32) ----------------
// qkvs2 f32 [n][128]: q 0-31, k 32-63, v 64-95, skip 96-127 ; e2b bf16 [i][32]
__global__ void attn2_kernel(const float* __restrict__ qkvs2, const unsigned short* __restrict__ e2b,
                             const int* __restrict__ srcs, const int* __restrict__ rowptr,
                             float* __restrict__ outp) {
  const int n = blockIdx.x;
  const int tid = threadIdx.x;
  const int c = tid & 31;
  const int beg = rowptr[n], end = rowptr[n + 1];
  const float qv = qkvs2[(size_t)n * 128 + c];
  float m = -INFINITY, den = 0.f, acc = 0.f;
  for (int i = beg; i < end; ++i) {
    const int s = srcs[i];
    const float ev = bf2f(e2b[(size_t)i * 32 + c]);
    const float kv = qkvs2[(size_t)s * 128 + 32 + c] + ev;
    const float vv = qkvs2[(size_t)s * 128 + 64 + c] + ev;
    float p = qv * kv;
#pragma unroll
    for (int off = 16; off; off >>= 1) p += __shfl_xor(p, off);
    p *= 0.17677669529663687f;
    const float mn = fmaxf(m, p);
    const float scale = __expf(m - mn);
    const float w = __expf(p - mn);
    den = den * scale + w;
    acc = acc * scale + w * vv;
    m = mn;
  }
  if (tid < 32) {
    float o = acc / (den + 1e-16f) + qkvs2[(size_t)n * 128 + 96 + c];
    outp[(size_t)n * CH + c] = fmaxf(o, 0.f);
  }
}

// ---------------- launcher ----------------
extern "C" void kernel_launch(void* const* d_in, const int* in_sizes, int n_in,
                              void* d_out, int out_size, void* d_ws, size_t ws_size,
                              hipStream_t stream) {
  const float* x   = (const float*)d_in[0];
  const float* lu  = (const float*)d_in[1];
  const int*   ei  = (const int*)d_in[2];
  const float* tt  = (const float*)d_in[3];
  const float* msg = (const float*)d_in[4];
  const float* tw  = (const float*)d_in[5];
  const float* tb  = (const float*)d_in[6];
  const float* Wq1 = (const float*)d_in[7];  const float* bq1 = (const float*)d_in[8];
  const float* Wk1 = (const float*)d_in[9];  const float* bk1 = (const float*)d_in[10];
  const float* Wv1 = (const float*)d_in[11]; const float* bv1 = (const float*)d_in[12];
  const float* We1 = (const float*)d_in[13];
  const float* Ws1 = (const float*)d_in[14]; const float* bs1 = (const float*)d_in[15];
  const float* Wq2 = (const float*)d_in[16]; const float* bq2 = (const float*)d_in[17];
  const float* Wk2 = (const float*)d_in[18]; const float* bk2 = (const float*)d_in[19];
  const float* Wv2 = (const float*)d_in[20]; const float* bv2 = (const float*)d_in[21];
  const float* We2 = (const float*)d_in[22];
  const float* Ws2 = (const float*)d_in[23]; const float* bs2 = (const float*)d_in[24];

  const int* srcp = ei;
  const int* dstp = ei + N_EDGES;

  char* p = (char*)d_ws;
  auto alloc = [&](size_t bytes) -> char* {
    char* r = p;
    p += (bytes + 255) & ~(size_t)255;
    return r;
  };
  float* rel    = (float*)alloc((size_t)N_EDGES * 4);
  int*   deg    = (int*)alloc((size_t)N_NODES * 4);
  int*   fill   = (int*)alloc((size_t)N_NODES * 4);
  int*   rowptr = (int*)alloc((size_t)(N_NODES + 1) * 4);
  int*   eid    = (int*)alloc((size_t)N_EDGES * 4);
  int*   srcs   = (int*)alloc((size_t)N_EDGES * 4);
  unsigned short* xa    = (unsigned short*)alloc((size_t)RT1 * 32768);
  unsigned short* W1f   = (unsigned short*)alloc((size_t)8 * 64 * 1024);  // 1024 cols
  unsigned short* We1f  = (unsigned short*)alloc((size_t)8 * 16 * 1024);  // 256 cols
  unsigned short* W2f   = (unsigned short*)alloc((size_t)8 * 8 * 1024);   // 128 cols
  unsigned short* We2f  = (unsigned short*)alloc((size_t)8 * 4 * 1024);   // 64 cols (32 real + pad)
  float* bcat1  = (float*)alloc(1024 * 4);
  float* bcat2  = (float*)alloc(128 * 4);
  unsigned short* ea    = (unsigned short*)alloc((size_t)RTE * 32768);    // 82 MB
  float* qkvs   = (float*)alloc((size_t)N_NODES * 1024 * 4);              // 41 MB
  unsigned short* e1b   = (unsigned short*)alloc((size_t)N_EDGES * 256 * 2);  // 82 MB
  unsigned short* ha    = (unsigned short*)alloc((size_t)RT1 * 32768);
  float* qkvs2  = (float*)alloc((size_t)N_NODES * 128 * 4);
  unsigned short* e2b   = (unsigned short*)alloc((size_t)N_EDGES * 32 * 2);
  float* outp   = (float*)d_out;

  hipMemsetAsync(deg, 0, (size_t)N_NODES * 4, stream);
  hipMemsetAsync(fill, 0, (size_t)N_NODES * 4, stream);
  hipMemsetAsync(We2f, 0, (size_t)8 * 4 * 1024 * 2, stream);
  hipMemsetAsync(ha, 0, (size_t)RT1 * 32768, stream);   // zero pad rows for node2 GEMM

  rel_kernel<<<625, 256, 0, stream>>>(lu, srcp, tt, rel, N_EDGES);
  count_kernel<<<625, 256, 0, stream>>>(dstp, deg, N_EDGES);
  scan_kernel<<<1, 1024, 0, stream>>>(deg, rowptr, N_NODES);
  scatter_kernel<<<625, 256, 0, stream>>>(dstp, rowptr, fill, eid, N_EDGES);

  // weight / input conversions to frag layout
  conv_x_kernel<<<ceildiv(RT1 * 64 * 32, 256), 256, 0, stream>>>(x, xa, N_NODES, RT1);
  conv_w_kernel<<<256, 256, 0, stream>>>(Wq1, W1f, 256, 0,   64);
  conv_w_kernel<<<256, 256, 0, stream>>>(Wk1, W1f, 256, 256, 64);
  conv_w_kernel<<<256, 256, 0, stream>>>(Wv1, W1f, 256, 512, 64);
  conv_w_kernel<<<256, 256, 0, stream>>>(Ws1, W1f, 256, 768, 64);
  conv_w_kernel<<<256, 256, 0, stream>>>(We1, We1f, 256, 0, 16);
  conv_w_kernel<<<32, 256, 0, stream>>>(Wq2, W2f, 32, 0,  8);
  conv_w_kernel<<<32, 256, 0, stream>>>(Wk2, W2f, 32, 32, 8);
  conv_w_kernel<<<32, 256, 0, stream>>>(Wv2, W2f, 32, 64, 8);
  conv_w_kernel<<<32, 256, 0, stream>>>(Ws2, W2f, 32, 96, 8);
  conv_w_kernel<<<32, 256, 0, stream>>>(We2, We2f, 32, 0, 4);
  concat4_kernel<<<4, 256, 0, stream>>>(bcat1, bq1, bk1, bv1, bs1, 256);
  concat4_kernel<<<1, 256, 0, stream>>>(bcat2, bq2, bk2, bv2, bs2, 32);

  // edge_attr (sorted, frag layout) + src_sorted
  build_ea_kernel<<<ceildiv(N_EDGES * 32, 256), 256, 0, stream>>>(rel, tw, tb, msg, eid, srcp, ea, srcs);

  // layer-1 GEMMs
  {
    dim3 g1(RT1, 4);
    gemm_mfma<1, true><<<g1, 256, 0, stream>>>(xa, W1f, bcat1, qkvs, RT1, N_NODES, 64, 1024, 1024);
    dim3 ge(RTE, 1);
    gemm_mfma<1, false><<<ge, 256, 0, stream>>>(ea, We1f, nullptr, e1b, RTE, N_EDGES, 16, 256, 256);
  }
  attn1_kernel<<<N_NODES, 256, 0, stream>>>(qkvs, e1b, srcs, rowptr, ha);

  // layer-2 GEMMs
  {
    dim3 g2(ceildiv(RT1, 2), 1);
    gemm_mfma<2, true><<<g2, 256, 0, stream>>>(ha, W2f, bcat2, qkvs2, RT1, N_NODES, 8, 128, 128);
    dim3 ge2(RTE / 4, 1);
    gemm_mfma<4, false><<<ge2, 256, 0, stream>>>(ea, We2f, nullptr, e2b, RTE, N_EDGES, 4, 32, 32);
  }
  attn2_kernel<<<N_NODES, 64, 0, stream>>>(qkvs2, e2b, srcs, rowptr, outp);
}

// Round 4
// 252.568 us; speedup vs baseline: 5.9986x; 1.8814x over previous
//
#include <hip/hip_runtime.h>
#include <math.h>

#define N_NODES 10000
#define N_EDGES 160000
#define D 256
#define H1 8
#define CH 32
#define TDIM 128
#define MSGD 128
#define RT1 157      // ceil(10000/64)
#define RTE 2500     // 160000/64

static inline int ceildiv(int a, int b) { return (a + b - 1) / b; }

typedef float f32x4 __attribute__((ext_vector_type(4)));
typedef short bf16x8 __attribute__((ext_vector_type(8)));

__device__ __forceinline__ unsigned short f2bf(float f) {
  unsigned int u = __builtin_bit_cast(unsigned int, f);
  u += 0x7FFFu + ((u >> 16) & 1u);   // RNE
  return (unsigned short)(u >> 16);
}
__device__ __forceinline__ float bf2f(unsigned short h) {
  unsigned int u = ((unsigned int)h) << 16;
  return __builtin_bit_cast(float, u);
}

// ---------------- prep ----------------
__global__ void count_kernel(const int* __restrict__ dstp, int* __restrict__ deg, int E) {
  for (int i = blockIdx.x * blockDim.x + threadIdx.x; i < E; i += gridDim.x * blockDim.x)
    atomicAdd(&deg[dstp[i]], 1);
}

// 1024 threads, each owns 10 contiguous elements; ~20 barriers total
__global__ void scan_kernel(const int* __restrict__ deg, int* __restrict__ rowptr, int n) {
  __shared__ int part[1024];
  const int tid = threadIdx.x;
  const int CHK = 10;                 // 1024*10 >= 10000
  int base = tid * CHK;
  int loc[CHK];
  int s = 0;
#pragma unroll
  for (int j = 0; j < CHK; ++j) {
    int idx = base + j;
    int v = (idx < n) ? deg[idx] : 0;
    loc[j] = s; s += v;
  }
  part[tid] = s;
  __syncthreads();
  for (int off = 1; off < 1024; off <<= 1) {
    int y = (tid >= off) ? part[tid - off] : 0;
    __syncthreads();
    part[tid] += y;
    __syncthreads();
  }
  int pre = tid ? part[tid - 1] : 0;
#pragma unroll
  for (int j = 0; j < CHK; ++j) {
    int idx = base + j;
    if (idx < n) rowptr[idx] = pre + loc[j];
  }
  if (tid == 1023) rowptr[n] = part[1023];
}

__global__ void scatter_kernel(const int* __restrict__ dstp, const int* __restrict__ rowptr,
                               int* __restrict__ fill, int* __restrict__ eid, int E) {
  for (int e = blockIdx.x * blockDim.x + threadIdx.x; e < E; e += gridDim.x * blockDim.x) {
    int d = dstp[e];
    int pos = atomicAdd(&fill[d], 1);
    eid[rowptr[d] + pos] = e;
  }
}

// sorted rel_t + sorted src
__global__ void relsort_kernel(const float* __restrict__ lu, const int* __restrict__ srcp,
                               const float* __restrict__ tt, const int* __restrict__ eid,
                               float* __restrict__ rel_s, int* __restrict__ srcs, int E) {
  for (int i = blockIdx.x * blockDim.x + threadIdx.x; i < E; i += gridDim.x * blockDim.x) {
    int e = eid[i];
    int s = srcp[e];
    srcs[i] = s;
    rel_s[i] = lu[s] - tt[e];
  }
}

// ---------------- operand-layout converters ----------------
// A frag layout (ushorts): addr(i,k) = rt*16384 + ks*2048 + rf*512 + (ir+16*kg)*8 + j
//   rt=i>>6, rf=(i>>4)&3, ir=i&15 ; ks=k>>5, kg=(k>>3)&3, j=k&7
// B frag layout: addr(k,c) = (ks*NFtot + (c>>4))*512 + ((c&15)+16*kg)*8 + j

__global__ void conv_x_kernel(const float* __restrict__ x, unsigned short* __restrict__ xa,
                              int M, int RT) {
  int t = blockIdx.x * blockDim.x + threadIdx.x;
  if (t >= RT * 64 * 32) return;
  int i = t >> 5, k8 = t & 31;
  int k = k8 * 8;
  union { uint4 q; unsigned short s[8]; } u;
  if (i < M) {
    const float4* px = (const float4*)(x + (size_t)i * 256 + k);
    float4 f0 = px[0], f1 = px[1];
    u.s[0]=f2bf(f0.x); u.s[1]=f2bf(f0.y); u.s[2]=f2bf(f0.z); u.s[3]=f2bf(f0.w);
    u.s[4]=f2bf(f1.x); u.s[5]=f2bf(f1.y); u.s[6]=f2bf(f1.z); u.s[7]=f2bf(f1.w);
  } else {
    u.q = make_uint4(0,0,0,0);
  }
  int rt=i>>6, rf=(i>>4)&3, ir=i&15, ks=k8>>2, kg=k8&3;
  *(uint4*)&xa[(size_t)rt*16384 + ks*2048 + rf*512 + (ir+16*kg)*8] = u.q;
}

__device__ __forceinline__ void wstore(const float* __restrict__ W, unsigned short* __restrict__ out,
                                       int Nin, int n_off, int NFtot, int k, int c) {
  int gc = n_off + c;
  int ks=k>>5, kg=(k>>3)&3, j=k&7, nf=gc>>4, ic=gc&15;
  out[(size_t)(ks*NFtot+nf)*512 + (ic+16*kg)*8 + j] = f2bf(W[(size_t)k*Nin + c]);
}

// all weight/bias conversions in one launch
__global__ void conv_all_kernel(const float* Wq1, const float* Wk1, const float* Wv1, const float* Ws1,
                                const float* We1, const float* Wq2, const float* Wk2, const float* Wv2,
                                const float* Ws2, const float* We2,
                                const float* bq1, const float* bk1, const float* bv1, const float* bs1,
                                const float* bq2, const float* bk2, const float* bv2, const float* bs2,
                                unsigned short* W1f, unsigned short* We1f, unsigned short* W2f,
                                unsigned short* We2f, float* bcat1, float* bcat2) {
  int t = blockIdx.x * blockDim.x + threadIdx.x;
  if (t < 262144) {               // W1f: 4 x 256x256
    int w = t >> 16, r = t & 65535, k = r >> 8, c = r & 255;
    const float* W = (w == 0) ? Wq1 : (w == 1) ? Wk1 : (w == 2) ? Wv1 : Ws1;
    wstore(W, W1f, 256, w * 256, 64, k, c);
  } else if (t < 327680) {        // We1f: 256x256
    int r = t - 262144, k = r >> 8, c = r & 255;
    wstore(We1, We1f, 256, 0, 16, k, c);
  } else if (t < 360448) {        // W2f: 4 x 256x32
    int r = t - 327680, w = r >> 13, r2 = r & 8191, k = r2 >> 5, c = r2 & 31;
    const float* W = (w == 0) ? Wq2 : (w == 1) ? Wk2 : (w == 2) ? Wv2 : Ws2;
    wstore(W, W2f, 32, w * 32, 8, k, c);
  } else if (t < 368640) {        // We2f: 256x32 (cols 32-63 pre-zeroed by memset)
    int r = t - 360448, k = r >> 5, c = r & 31;
    wstore(We2, We2f, 32, 0, 4, k, c);
  } else if (t < 369792) {        // biases
    int r = t - 368640;
    if (r < 1024) {
      const float* b = (r < 256) ? bq1 : (r < 512) ? bk1 : (r < 768) ? bv1 : bs1;
      bcat1[r] = b[r & 255];
    } else {
      int r2 = r - 1024;
      const float* b = (r2 < 32) ? bq2 : (r2 < 64) ? bk2 : (r2 < 96) ? bv2 : bs2;
      bcat2[r2] = b[r2 & 31];
    }
  }
}

// ---------------- MFMA GEMM ----------------
// Wave tile 64x64 (4x4 frags), 4 waves/block. K=256 (8 steps of 32), K-order
// staggered per block (ks = ksi ^ (bx&7)) to decorrelate shared-B L2 reads.
// SYNTH: A rows synthesized (time-encoding cos + msg gather) per exclusive edge tile.
// EPI 0: f32 single out (direct, coalesced). EPI 1: bf16 single out via LDS tile.
// EPI 2: node1 quad routing by blockIdx.y: y0->qf f32, y1/y2->kvb bf16 (col0 0/256), y3->sf f32.
template <int WRW, int EPI, bool SYNTH>
__global__ __launch_bounds__(256)
void gemm_mfma(const unsigned short* __restrict__ A, const unsigned short* __restrict__ B,
               const float* __restrict__ bias, void* __restrict__ C0, void* __restrict__ C1,
               void* __restrict__ C2, int RT, int M, int NFtot, int Creal, int Cstride, int dcol0,
               const float* __restrict__ rel, const float* __restrict__ tw,
               const float* __restrict__ tb, const float* __restrict__ msg,
               const int* __restrict__ eid) {
  constexpr int WCW = 4 / WRW;
  constexpr int ACH = WRW * 256;
  constexpr int BCH = WCW * 256;
  constexpr int CH_TOT = ACH + BCH;
  constexpr int PER_T = CH_TOT / 256;
  constexpr int PA = ACH / 256;
  constexpr int ROWS = WRW * 64;
  constexpr int COLS = WCW * 64;
  constexpr int CSTR = COLS + 8;
  constexpr int STAGE_B = CH_TOT * 16;
  constexpr int CTILE_B = (EPI != 0) ? ROWS * CSTR * 2 : 0;
  constexpr int LDS_B = (STAGE_B > CTILE_B) ? STAGE_B : CTILE_B;
  __shared__ char ldsraw[LDS_B];
  uint4* lds = (uint4*)ldsraw;

  const int tid = threadIdx.x;
  const int wid = tid >> 6, lane = tid & 63;
  const int wr = (WRW == 1) ? 0 : ((WRW == 4) ? wid : (wid >> 1));
  const int wc = (WRW == 1) ? wid : ((WRW == 4) ? 0 : (wid & 1));
  const int rt0 = blockIdx.x * WRW;
  const int n0f = blockIdx.y * (WCW * 4);
  const int phase = blockIdx.x & 7;

  auto fetchA = [&](int ks, int c) -> uint4 {
    int rt = rt0 + (c >> 8);
    if (rt >= RT) rt = RT - 1;
    if constexpr (SYNTH) {
      int rem = c & 255;
      int rf = rem >> 6, r2 = rem & 63, ir = r2 & 15, kg = r2 >> 4;
      int i = rt * 64 + rf * 16 + ir;
      int k8 = ks * 4 + kg;
      union { uint4 q; unsigned short s[8]; } u;
      if (k8 < 16) {
        float r = rel[i];
        const float4* twp = (const float4*)(tw + k8 * 8);
        const float4* tbp = (const float4*)(tb + k8 * 8);
        float4 w0 = twp[0], w1 = twp[1], b0 = tbp[0], b1 = tbp[1];
        u.s[0]=f2bf(__cosf(r*w0.x+b0.x)); u.s[1]=f2bf(__cosf(r*w0.y+b0.y));
        u.s[2]=f2bf(__cosf(r*w0.z+b0.z)); u.s[3]=f2bf(__cosf(r*w0.w+b0.w));
        u.s[4]=f2bf(__cosf(r*w1.x+b1.x)); u.s[5]=f2bf(__cosf(r*w1.y+b1.y));
        u.s[6]=f2bf(__cosf(r*w1.z+b1.z)); u.s[7]=f2bf(__cosf(r*w1.w+b1.w));
      } else {
        int e = eid[i];
        const float4* pm = (const float4*)(msg + (size_t)e * MSGD + (k8 - 16) * 8);
        float4 f0 = pm[0], f1 = pm[1];
        u.s[0]=f2bf(f0.x); u.s[1]=f2bf(f0.y); u.s[2]=f2bf(f0.z); u.s[3]=f2bf(f0.w);
        u.s[4]=f2bf(f1.x); u.s[5]=f2bf(f1.y); u.s[6]=f2bf(f1.z); u.s[7]=f2bf(f1.w);
      }
      return u.q;
    } else {
      return *(const uint4*)(A + (size_t)rt * 16384 + ks * 2048 + (size_t)(c & 255) * 8);
    }
  };
  auto fetchB = [&](int ks, int cb) -> uint4 {
    return *(const uint4*)(B + ((size_t)ks * NFtot + n0f) * 512 + (size_t)cb * 8);
  };

  uint4 st[PER_T];
  {
    int ks0 = 0 ^ phase;
#pragma unroll
    for (int p = 0; p < PA; ++p) st[p] = fetchA(ks0, tid + p * 256);
#pragma unroll
    for (int p = PA; p < PER_T; ++p) st[p] = fetchB(ks0, tid + (p - PA) * 256);
  }

  f32x4 acc[4][4];
#pragma unroll
  for (int i = 0; i < 4; ++i)
#pragma unroll
    for (int j = 0; j < 4; ++j) acc[i][j] = (f32x4){0.f, 0.f, 0.f, 0.f};

  for (int ksi = 0; ksi < 8; ++ksi) {
    __syncthreads();
#pragma unroll
    for (int p = 0; p < PER_T; ++p) lds[tid + p * 256] = st[p];
    if (ksi < 7) {
      int ksn = (ksi + 1) ^ phase;
#pragma unroll
      for (int p = 0; p < PA; ++p) st[p] = fetchA(ksn, tid + p * 256);
#pragma unroll
      for (int p = PA; p < PER_T; ++p) st[p] = fetchB(ksn, tid + (p - PA) * 256);
    }
    __syncthreads();
    bf16x8 a[4], b[4];
#pragma unroll
    for (int rf = 0; rf < 4; ++rf) a[rf] = *(const bf16x8*)&lds[(wr * 4 + rf) * 64 + lane];
#pragma unroll
    for (int cf = 0; cf < 4; ++cf) b[cf] = *(const bf16x8*)&lds[ACH + (wc * 4 + cf) * 64 + lane];
#pragma unroll
    for (int rf = 0; rf < 4; ++rf)
#pragma unroll
      for (int cf = 0; cf < 4; ++cf)
        acc[rf][cf] = __builtin_amdgcn_mfma_f32_16x16x32_bf16(a[rf], b[cf], acc[rf][cf], 0, 0, 0);
  }

  // ---- epilogue ----  C/D frag: col=lane&15, row=(lane>>4)*4+reg
  const int y = blockIdx.y;
  bool bf16path;
  void* dstp_; int cstr_, dc0_, bcol0_;
  if constexpr (EPI == 0) { bf16path = false; dstp_ = C0; cstr_ = Cstride; dc0_ = 0; bcol0_ = blockIdx.y * COLS; }
  else if constexpr (EPI == 1) { bf16path = true; dstp_ = C0; cstr_ = Cstride; dc0_ = dcol0; bcol0_ = 0; }
  else {
    if (y == 0)      { bf16path = false; dstp_ = C0; cstr_ = 256; dc0_ = 0;   bcol0_ = 0; }
    else if (y == 1) { bf16path = true;  dstp_ = C1; cstr_ = 512; dc0_ = 0;   bcol0_ = 256; }
    else if (y == 2) { bf16path = true;  dstp_ = C1; cstr_ = 512; dc0_ = 256; bcol0_ = 512; }
    else             { bf16path = false; dstp_ = C2; cstr_ = 256; dc0_ = 0;   bcol0_ = 768; }
  }

  if (!bf16path) {
    float* dst = (float*)dstp_;
    const int row0 = (rt0 + wr) * 64 + ((lane >> 4) * 4);
    const int cb2 = wc * 64 + (lane & 15);
#pragma unroll
    for (int cf = 0; cf < 4; ++cf) {
      int c = cb2 + cf * 16;
      if (c >= Creal) continue;
      float bv = bias ? bias[bcol0_ + c] : 0.f;
#pragma unroll
      for (int rf = 0; rf < 4; ++rf) {
#pragma unroll
        for (int j = 0; j < 4; ++j) {
          int r = row0 + rf * 16 + j;
          if (r < M) dst[(size_t)r * cstr_ + c] = acc[rf][cf][j] + bv;
        }
      }
    }
  } else {
    __syncthreads();   // staging reads done; reuse LDS for C tile
    unsigned short* cl = (unsigned short*)ldsraw;
    const int r0 = wr * 64 + ((lane >> 4) * 4);
    const int c0l = wc * 64 + (lane & 15);
#pragma unroll
    for (int cf = 0; cf < 4; ++cf) {
      int c = c0l + cf * 16;
      float bv = bias ? bias[bcol0_ + c] : 0.f;
#pragma unroll
      for (int rf = 0; rf < 4; ++rf)
#pragma unroll
        for (int j = 0; j < 4; ++j)
          cl[(size_t)(r0 + rf * 16 + j) * CSTR + c] = f2bf(acc[rf][cf][j] + bv);
    }
    __syncthreads();
    const int CPC = Creal >> 3;
    const int total = ROWS * CPC;
    unsigned short* dst = (unsigned short*)dstp_;
    for (int id = tid; id < total; id += 256) {
      int row = id / CPC, colc = (id - row * CPC) * 8;
      int gr = rt0 * 64 + row;
      if (gr < M)
        *(uint4*)&dst[(size_t)gr * cstr_ + dc0_ + colc] = *(const uint4*)&cl[(size_t)row * CSTR + colc];
    }
  }
}

// ---------------- attention layer 1 (8 heads x 32, concat) ----------------
// 1 wave per dst node; lane -> (head lane>>3, 4 channels (lane&7)*4). Online softmax.
// q,s f32 [n][256]; k,v bf16 kvb[n][512] (k 0-255, v 256-511); e1b bf16 [i][256] sorted.
__global__ __launch_bounds__(64)
void attn1_kernel(const float* __restrict__ qf, const unsigned short* __restrict__ kvb,
                  const float* __restrict__ sf, const unsigned short* __restrict__ e1b,
                  const int* __restrict__ srcs, const int* __restrict__ rowptr,
                  unsigned short* __restrict__ ha) {
  const int n = blockIdx.x;
  const int lane = threadIdx.x;
  const int h = lane >> 3;
  const int c0 = (lane & 7) * 4;
  const int off = h * 32 + c0;
  const int beg = rowptr[n], end = rowptr[n + 1];
  const float4 q = *(const float4*)&qf[(size_t)n * 256 + off];
  float m = -INFINITY, den = 0.f;
  float a0 = 0.f, a1 = 0.f, a2 = 0.f, a3 = 0.f;
  for (int i = beg; i < end; ++i) {
    const int s = srcs[i];
    ushort4 ev = *(const ushort4*)&e1b[(size_t)i * 256 + off];
    ushort4 kk = *(const ushort4*)&kvb[(size_t)s * 512 + off];
    ushort4 vv = *(const ushort4*)&kvb[(size_t)s * 512 + 256 + off];
    float e0 = bf2f(ev.x), e1 = bf2f(ev.y), e2 = bf2f(ev.z), e3 = bf2f(ev.w);
    float k0 = bf2f(kk.x) + e0, k1 = bf2f(kk.y) + e1, k2 = bf2f(kk.z) + e2, k3 = bf2f(kk.w) + e3;
    float v0 = bf2f(vv.x) + e0, v1 = bf2f(vv.y) + e1, v2 = bf2f(vv.z) + e2, v3 = bf2f(vv.w) + e3;
    float p = q.x * k0 + q.y * k1 + q.z * k2 + q.w * k3;
    p += __shfl_xor(p, 1); p += __shfl_xor(p, 2); p += __shfl_xor(p, 4);
    p *= 0.17677669529663687f;   // 1/sqrt(32)
    const float mn = fmaxf(m, p);
    const float sc = __expf(m - mn);
    const float w = __expf(p - mn);
    den = den * sc + w;
    a0 = a0 * sc + w * v0; a1 = a1 * sc + w * v1;
    a2 = a2 * sc + w * v2; a3 = a3 * sc + w * v3;
    m = mn;
  }
  const float inv = 1.f / (den + 1e-16f);
  const float4 sk = *(const float4*)&sf[(size_t)n * 256 + off];
  float o0 = fmaxf(a0 * inv + sk.x, 0.f);
  float o1 = fmaxf(a1 * inv + sk.y, 0.f);
  float o2 = fmaxf(a2 * inv + sk.z, 0.f);
  float o3 = fmaxf(a3 * inv + sk.w, 0.f);
  // write h in A-frag layout: ch = h*32+c0+j ; ks=h, kg=(c0>>3), j'=(c0&7)+j
  int rt = n >> 6, rf = (n >> 4) & 3, ir = n & 15;
  int kg = (lane & 7) >> 1, jj = 4 * (lane & 1);
  ushort4 w4;
  w4.x = f2bf(o0); w4.y = f2bf(o1); w4.z = f2bf(o2); w4.w = f2bf(o3);
  *(ushort4*)&ha[(size_t)rt * 16384 + h * 2048 + rf * 512 + (ir + 16 * kg) * 8 + jj] = w4;
}

// ---------------- attention layer 2 (1 head x 32) ----------------
// qkvs2 f32 [n][128]: q 0-31, k 32-63, v 64-95, s 96-127 ; e2b bf16 [i][32]
__global__ __launch_bounds__(64)
void attn2_kernel(const float* __restrict__ qkvs2, const unsigned short* __restrict__ e2b,
                  const int* __restrict__ srcs, const int* __restrict__ rowptr,
                  float* __restrict__ outp) {
  const int n = blockIdx.x;
  const int tid = threadIdx.x;
  const int c = tid & 31;
  const int beg = rowptr[n], end = rowptr[n + 1];
  const float qv = qkvs2[(size_t)n * 128 + c];
  float m = -INFINITY, den = 0.f, acc = 0.f;
  for (int i = beg; i < end; ++i) {
    const int s = srcs[i];
    const float ev = bf2f(e2b[(size_t)i * 32 + c]);
    const float kv = qkvs2[(size_t)s * 128 + 32 + c] + ev;
    const float vv = qkvs2[(size_t)s * 128 + 64 + c] + ev;
    float p = qv * kv;
#pragma unroll
    for (int off = 16; off; off >>= 1) p += __shfl_xor(p, off);
    p *= 0.17677669529663687f;
    const float mn = fmaxf(m, p);
    const float sc = __expf(m - mn);
    const float w = __expf(p - mn);
    den = den * sc + w;
    acc = acc * sc + w * vv;
    m = mn;
  }
  if (tid < 32) {
    float o = acc / (den + 1e-16f) + qkvs2[(size_t)n * 128 + 96 + c];
    outp[(size_t)n * CH + c] = fmaxf(o, 0.f);
  }
}

// ---------------- launcher ----------------
extern "C" void kernel_launch(void* const* d_in, const int* in_sizes, int n_in,
                              void* d_out, int out_size, void* d_ws, size_t ws_size,
                              hipStream_t stream) {
  const float* x   = (const float*)d_in[0];
  const float* lu  = (const float*)d_in[1];
  const int*   ei  = (const int*)d_in[2];
  const float* tt  = (const float*)d_in[3];
  const float* msg = (const float*)d_in[4];
  const float* tw  = (const float*)d_in[5];
  const float* tb  = (const float*)d_in[6];
  const float* Wq1 = (const float*)d_in[7];  const float* bq1 = (const float*)d_in[8];
  const float* Wk1 = (const float*)d_in[9];  const float* bk1 = (const float*)d_in[10];
  const float* Wv1 = (const float*)d_in[11]; const float* bv1 = (const float*)d_in[12];
  const float* We1 = (const float*)d_in[13];
  const float* Ws1 = (const float*)d_in[14]; const float* bs1 = (const float*)d_in[15];
  const float* Wq2 = (const float*)d_in[16]; const float* bq2 = (const float*)d_in[17];
  const float* Wk2 = (const float*)d_in[18]; const float* bk2 = (const float*)d_in[19];
  const float* Wv2 = (const float*)d_in[20]; const float* bv2 = (const float*)d_in[21];
  const float* We2 = (const float*)d_in[22];
  const float* Ws2 = (const float*)d_in[23]; const float* bs2 = (const float*)d_in[24];

  const int* srcp = ei;
  const int* dstp = ei + N_EDGES;

  char* p = (char*)d_ws;
  auto alloc = [&](size_t bytes) -> char* {
    char* r = p;
    p += (bytes + 255) & ~(size_t)255;
    return r;
  };
  int*   deg    = (int*)alloc((size_t)N_NODES * 4);
  int*   fill   = (int*)alloc((size_t)N_NODES * 4);
  int*   rowptr = (int*)alloc((size_t)(N_NODES + 1) * 4);
  int*   eid    = (int*)alloc((size_t)N_EDGES * 4);
  int*   srcs   = (int*)alloc((size_t)N_EDGES * 4);
  float* rel_s  = (float*)alloc((size_t)N_EDGES * 4);
  unsigned short* xa   = (unsigned short*)alloc((size_t)RT1 * 32768);
  unsigned short* W1f  = (unsigned short*)alloc((size_t)8 * 64 * 1024);   // 1024 cols
  unsigned short* We1f = (unsigned short*)alloc((size_t)8 * 16 * 1024);   // 256 cols
  unsigned short* W2f  = (unsigned short*)alloc((size_t)8 * 8 * 1024);    // 128 cols
  unsigned short* We2f = (unsigned short*)alloc((size_t)8 * 4 * 1024);    // 64 cols (32 real + pad)
  float* bcat1  = (float*)alloc(1024 * 4);
  float* bcat2  = (float*)alloc(128 * 4);
  float* qf     = (float*)alloc((size_t)N_NODES * 256 * 4);
  unsigned short* kvb = (unsigned short*)alloc((size_t)N_NODES * 512 * 2);
  float* sf     = (float*)alloc((size_t)N_NODES * 256 * 4);
  unsigned short* e1b = (unsigned short*)alloc((size_t)N_EDGES * 256 * 2);   // 82 MB
  unsigned short* ha  = (unsigned short*)alloc((size_t)RT1 * 32768);
  float* qkvs2  = (float*)alloc((size_t)N_NODES * 128 * 4);
  unsigned short* e2b = (unsigned short*)alloc((size_t)N_EDGES * 32 * 2);
  float* outp   = (float*)d_out;

  hipMemsetAsync(deg, 0, (size_t)N_NODES * 4, stream);
  hipMemsetAsync(fill, 0, (size_t)N_NODES * 4, stream);
  hipMemsetAsync(We2f, 0, (size_t)8 * 4 * 1024 * 2, stream);
  hipMemsetAsync(ha + (size_t)(RT1 - 1) * 16384, 0, 32768, stream);  // zero pad rows 10000-10047

  count_kernel<<<625, 256, 0, stream>>>(dstp, deg, N_EDGES);
  scan_kernel<<<1, 1024, 0, stream>>>(deg, rowptr, N_NODES);
  scatter_kernel<<<625, 256, 0, stream>>>(dstp, rowptr, fill, eid, N_EDGES);
  relsort_kernel<<<625, 256, 0, stream>>>(lu, srcp, tt, eid, rel_s, srcs, N_EDGES);

  conv_x_kernel<<<ceildiv(RT1 * 64 * 32, 256), 256, 0, stream>>>(x, xa, N_NODES, RT1);
  conv_all_kernel<<<ceildiv(369792, 256), 256, 0, stream>>>(
      Wq1, Wk1, Wv1, Ws1, We1, Wq2, Wk2, Wv2, Ws2, We2,
      bq1, bk1, bv1, bs1, bq2, bk2, bv2, bs2,
      W1f, We1f, W2f, We2f, bcat1, bcat2);

  // node1: quad-routed epilogue (q f32 | k bf16 | v bf16 | s f32)
  gemm_mfma<1, 2, false><<<dim3(RT1, 4), 256, 0, stream>>>(
      xa, W1f, bcat1, qf, kvb, sf, RT1, N_NODES, 64, 256, 0, 0,
      nullptr, nullptr, nullptr, nullptr, nullptr);
  // e1: synthesized A (cos + msg), bf16 out
  gemm_mfma<1, 1, true><<<dim3(RTE, 1), 256, 0, stream>>>(
      nullptr, We1f, nullptr, e1b, nullptr, nullptr, RTE, N_EDGES, 16, 256, 256, 0,
      rel_s, tw, tb, msg, eid);
  attn1_kernel<<<N_NODES, 64, 0, stream>>>(qf, kvb, sf, e1b, srcs, rowptr, ha);

  // node2: f32 out [n][128]
  gemm_mfma<2, 0, false><<<dim3(ceildiv(RT1, 2), 1), 256, 0, stream>>>(
      ha, W2f, bcat2, qkvs2, nullptr, nullptr, RT1, N_NODES, 8, 128, 128, 0,
      nullptr, nullptr, nullptr, nullptr, nullptr);
  // e2: synthesized A, bf16 out [i][32]
  gemm_mfma<4, 1, true><<<dim3(RTE / 4, 1), 256, 0, stream>>>(
      nullptr, We2f, nullptr, e2b, nullptr, nullptr, RTE, N_EDGES, 4, 32, 32, 0,
      rel_s, tw, tb, msg, eid);
  attn2_kernel<<<N_NODES, 64, 0, stream>>>(qkvs2, e2b, srcs, rowptr, outp);
}